// Round 2
// baseline (309.317 us; speedup 1.0000x reference)
//
#include <hip/hip_runtime.h>
#include <hip/hip_bf16.h>

// StreamingPCEN: x [B=16, MICS=4, T=2048, F=257] fp32.
// M_t = (1-s) M_{t-1} + s x_t, M_0 = x_0; out = (x/(M+eps)^alpha + delta)^r - delta^r.
//
// EXACT two-phase chunked scan (EMA is linear, so it decomposes):
//   phase1: thread (bm,c,f) scans its 128-frame chunk from zero state
//           (c==0: from the fixed point m=x_0) and writes the chunk-end
//           state mloc[bm][c][f] to the 1 MB workspace. Reads x exactly once.
//   phase2: thread (bm,c,f) rebuilds its exact carry-in with <=15 fmas
//           (E_c = a^128 E_{c-1} + mloc_c; a^128 via 7 squarings), then runs
//           the 128 output frames. x reads hit the L3 that phase1 populated.
// This removes the 256-frame warmup replay of the previous kernel (logical
// reads 2.81x -> 2x, HBM reads ~1.76x -> ~1x+L3) and makes the result exact.
//
// Round-1 post-mortem: VGPR_Count=28 proved the 16-deep load batches were
// re-serialized by regalloc under bare __launch_bounds__(256) -> MLP~1,
// latency-bound at 2.9 TB/s. Fixes here: __launch_bounds__(64,4) (VGPR
// budget 128, matching the grid's 4 waves/SIMD) so the batch survives, and
// 64-thread blocks (4112 blocks = 16.06/CU) to shrink the tail from +25%
// (1028 blocks = 4.01/CU) to +6%.

#define EPS 1e-6f

constexpr int BM = 64;       // B*MICS
constexpr int T  = 2048;
constexpr int F  = 257;
constexpr int L  = 128;      // frames per chunk
constexpr int C  = T / L;    // 16 chunks
constexpr int NWORK = BM * C * F;   // 263,168
constexpr int BLK   = 64;
constexpr int NBLK  = NWORK / BLK;  // 4112
constexpr int BATCH = 16;    // loads in flight per wave

// Raw gfx950 hardware transcendentals (v_exp_f32 = 2^x, v_log_f32 = log2 x).
__device__ __forceinline__ float fast_exp2(float x) { return __builtin_amdgcn_exp2f(x); }
__device__ __forceinline__ float fast_log2(float x) { return __builtin_amdgcn_logf(x); }

__device__ __forceinline__ float pcen_nl(float xv, float m, float alpha,
                                         float delta, float r, float dr) {
  float inner = fmaf(xv, fast_exp2(-alpha * fast_log2(m + EPS)), delta);
  return fast_exp2(r * fast_log2(inner)) - dr;
}

__device__ __forceinline__ void decompose(int idx, int& bm, int& c, int& f) {
  bm = idx / (C * F);
  int rem = idx - bm * (C * F);
  c = rem / F;
  f = rem - c * F;
}

// ---------------- phase 1: per-chunk local EMA end-state ----------------
__global__ __launch_bounds__(BLK, 4) void pcen_phase1(
    const float* __restrict__ x, const float* __restrict__ s_p,
    float* __restrict__ mloc) {
  int idx = blockIdx.x * BLK + threadIdx.x;
  const float s = s_p[0];
  const float a = 1.0f - s;

  int bm, c, f;
  decompose(idx, bm, c, f);

  const float* xp = x + (size_t)bm * T * F + (size_t)c * L * F + f;

  // c==0: m = x_0 is the fixed point of the frame-0 update (a*x0+s*x0 = x0),
  // so the standard loop over frames 0..127 yields the exact E_0.
  float m = (c == 0) ? xp[0] : 0.0f;

  for (int b = 0; b < L / BATCH; ++b) {
    float xv[BATCH];
    #pragma unroll
    for (int k = 0; k < BATCH; ++k) xv[k] = xp[k * F];
    #pragma unroll
    for (int k = 0; k < BATCH; ++k) m = fmaf(a, m, s * xv[k]);
    xp += BATCH * F;
  }
  mloc[idx] = m;  // layout [bm][c][f] == idx order, coalesced
}

// ---------------- phase 2: exact carry + output ----------------
__global__ __launch_bounds__(BLK, 4) void pcen_phase2(
    const float* __restrict__ x, const float* __restrict__ s_p,
    const float* __restrict__ alpha_p, const float* __restrict__ delta_p,
    const float* __restrict__ r_p, const float* __restrict__ mloc,
    float* __restrict__ out) {
  int idx = blockIdx.x * BLK + threadIdx.x;

  const float s     = s_p[0];
  const float a     = 1.0f - s;
  const float alpha = alpha_p[0];
  const float delta = delta_p[0];
  const float r     = r_p[0];
  const float dr    = fast_exp2(r * fast_log2(delta));

  // a^128 by 7 squarings (exact-ish; ~0.0392 for s=0.025)
  float aL = a;
  #pragma unroll
  for (int i = 0; i < 7; ++i) aL *= aL;

  int bm, c, f;
  decompose(idx, bm, c, f);

  const size_t base = (size_t)bm * T * F + (size_t)c * L * F + f;
  const float* xp = x + base;
  float*       op = out + base;

  // exact carry-in: E_{c-1} = state after last frame of chunk c-1
  float m;
  if (c == 0) {
    m = xp[0];  // fixed-point init, same trick as phase1
  } else {
    const float* mp = mloc + bm * (C * F) + f;
    m = mp[0];  // E_0
    for (int cc = 1; cc < c; ++cc) m = fmaf(aL, m, mp[cc * F]);
  }

  for (int b = 0; b < L / BATCH; ++b) {
    float xv[BATCH], mv[BATCH];
    #pragma unroll
    for (int k = 0; k < BATCH; ++k) xv[k] = xp[k * F];
    #pragma unroll
    for (int k = 0; k < BATCH; ++k) {   // serial dependency chain (cheap fmas)
      m = fmaf(a, m, s * xv[k]);
      mv[k] = m;
    }
    #pragma unroll
    for (int k = 0; k < BATCH; ++k) {   // independent -> transcendental ILP
      op[k * F] = pcen_nl(xv[k], mv[k], alpha, delta, r, dr);
    }
    xp += BATCH * F;
    op += BATCH * F;
  }
}

// ---------------- fallback (no workspace): truncated-history single pass ----
constexpr int H = 256;
__global__ __launch_bounds__(BLK, 4) void pcen_fallback(
    const float* __restrict__ x, const float* __restrict__ s_p,
    const float* __restrict__ alpha_p, const float* __restrict__ delta_p,
    const float* __restrict__ r_p, float* __restrict__ out) {
  int idx = blockIdx.x * BLK + threadIdx.x;

  const float s     = s_p[0];
  const float a     = 1.0f - s;
  const float alpha = alpha_p[0];
  const float delta = delta_p[0];
  const float r     = r_p[0];
  const float dr    = fast_exp2(r * fast_log2(delta));

  int bm, c, f;
  decompose(idx, bm, c, f);

  const size_t col = (size_t)bm * T * F + f;
  const float* xcol = x + col;
  float*       ocol = out + col;

  const int tstart = c * L;
  int t0 = tstart - H;
  if (t0 < 0) t0 = 0;

  float m;
  int t;
  if (t0 == 0) { m = xcol[0]; t = 0; }
  else         { m = 0.0f;    t = t0; }

  {
    const float* p = xcol + (size_t)t * F;
    int nwarm = tstart - t;
    for (int b = 0; b < nwarm; b += BATCH) {
      float xv[BATCH];
      #pragma unroll
      for (int k = 0; k < BATCH; ++k) xv[k] = p[k * F];
      #pragma unroll
      for (int k = 0; k < BATCH; ++k) m = fmaf(a, m, s * xv[k]);
      p += BATCH * F;
    }
  }
  {
    const float* p  = xcol + (size_t)tstart * F;
    float*       op = ocol + (size_t)tstart * F;
    for (int b = 0; b < L / BATCH; ++b) {
      float xv[BATCH], mv[BATCH];
      #pragma unroll
      for (int k = 0; k < BATCH; ++k) xv[k] = p[k * F];
      #pragma unroll
      for (int k = 0; k < BATCH; ++k) { m = fmaf(a, m, s * xv[k]); mv[k] = m; }
      #pragma unroll
      for (int k = 0; k < BATCH; ++k)
        op[k * F] = pcen_nl(xv[k], mv[k], alpha, delta, r, dr);
      p  += BATCH * F;
      op += BATCH * F;
    }
  }
}

extern "C" void kernel_launch(void* const* d_in, const int* in_sizes, int n_in,
                              void* d_out, int out_size, void* d_ws, size_t ws_size,
                              hipStream_t stream) {
  const float* x     = (const float*)d_in[0];
  const float* s     = (const float*)d_in[1];
  const float* alpha = (const float*)d_in[2];
  const float* delta = (const float*)d_in[3];
  const float* r     = (const float*)d_in[4];
  float* out = (float*)d_out;

  if (d_ws != nullptr && ws_size >= (size_t)NWORK * sizeof(float)) {
    float* mloc = (float*)d_ws;
    pcen_phase1<<<NBLK, BLK, 0, stream>>>(x, s, mloc);
    pcen_phase2<<<NBLK, BLK, 0, stream>>>(x, s, alpha, delta, r, mloc, out);
  } else {
    pcen_fallback<<<NBLK, BLK, 0, stream>>>(x, s, alpha, delta, r, out);
  }
}

// Round 3
// 300.955 us; speedup vs baseline: 1.0278x; 1.0278x over previous
//
#include <hip/hip_runtime.h>
#include <hip/hip_bf16.h>

// StreamingPCEN: x [B=16, MICS=4, T=2048, F=257] fp32.
// M_t = (1-s) M_{t-1} + s x_t, M_0 = x_0; out = (x/(M+eps)^alpha + delta)^r - delta^r.
//
// Round-2 post-mortem: both prior structures issued ONE dword (256 B/wave)
// per frame step and relied on the compiler to keep cross-iteration load
// batches alive -- it never did (r1 VGPR=28; r0/r1/r2 all ~2.9 TB/s, the
// MLP=1 latency equilibrium). This revision makes MLP structural:
//
//   * One wave per (bm, chunk). Lane l owns columns {l, l+64, l+128, l+192},
//     lane 0 additionally f=256. Per frame the wave issues 4 contiguous
//     256 B loads sharing ONE vaddr with imm offsets 0/256/512/768 (+1
//     uniform tail load) -- always clustered, 1028 B in flight per frame.
//   * L=32, C=64 -> 4096 waves = 16 waves/CU. Demand at one-cluster MLP:
//     16 x 1028 B / 900 cy = 18 B/cy/CU -> 11 TB/s >> HBM -> BW-bound.
//   * L=32 kills the warmup-replay option, so: EXACT two-phase scan.
//     phase1 writes per-chunk end states mloc[bm][c][f] (4 MB ws, x read
//     once). phase2 rebuilds the exact carry with <=63 fmas over L2/L3-
//     resident mloc (a^32 by 5 squarings), then emits the 32 output frames;
//     its x reads hit the L3 phase1 populated. NT stores for out.

#define EPS 1e-6f

constexpr int BM = 64;        // B*MICS
constexpr int T  = 2048;
constexpr int F  = 257;
constexpr int L  = 32;        // frames per chunk
constexpr int C  = T / L;     // 64 chunks
constexpr int NBLK = BM * C;  // 4096 single-wave blocks
constexpr size_t MLOC_BYTES = (size_t)BM * C * F * sizeof(float);  // ~4.02 MB

// Raw gfx950 hardware transcendentals (v_exp_f32 = 2^x, v_log_f32 = log2 x).
__device__ __forceinline__ float fast_exp2(float x) { return __builtin_amdgcn_exp2f(x); }
__device__ __forceinline__ float fast_log2(float x) { return __builtin_amdgcn_logf(x); }

__device__ __forceinline__ float pcen_nl(float xv, float m, float alpha,
                                         float delta, float r, float dr) {
  float inner = fmaf(xv, fast_exp2(-alpha * fast_log2(m + EPS)), delta);
  return fast_exp2(r * fast_log2(inner)) - dr;
}

// ---------------- phase 1: per-chunk local EMA end states ----------------
__global__ __launch_bounds__(64, 4) void pcen_phase1(
    const float* __restrict__ x, const float* __restrict__ s_p,
    float* __restrict__ mloc) {
  const int b  = blockIdx.x;
  const int l  = threadIdx.x;          // lane 0..63
  const int bm = b >> 6;               // b / C
  const int c  = b & (C - 1);          // b % C

  const float s = s_p[0];
  const float a = 1.0f - s;

  const float* row = x + ((size_t)bm * T + (size_t)c * L) * F;

  float m0, m1, m2, m3, m4;
  if (c == 0) {
    // fixed-point init: m = x_0 makes the frame-0 update a no-op,
    // so the uniform 32-frame loop yields the exact end state.
    m0 = row[l]; m1 = row[l + 64]; m2 = row[l + 128]; m3 = row[l + 192];
    m4 = row[256];
  } else {
    m0 = m1 = m2 = m3 = m4 = 0.0f;
  }

  const float* p = row;
  #pragma unroll 4
  for (int t = 0; t < L; ++t) {
    float x0 = p[l];        // one vaddr, imm offsets 0/256/512/768 B
    float x1 = p[l + 64];
    float x2 = p[l + 128];
    float x3 = p[l + 192];
    float x4 = p[256];      // uniform tail column
    m0 = fmaf(a, m0, s * x0);
    m1 = fmaf(a, m1, s * x1);
    m2 = fmaf(a, m2, s * x2);
    m3 = fmaf(a, m3, s * x3);
    m4 = fmaf(a, m4, s * x4);
    p += F;
  }

  float* mp = mloc + ((size_t)bm * C + c) * F;
  mp[l] = m0; mp[l + 64] = m1; mp[l + 128] = m2; mp[l + 192] = m3;
  if (l == 0) mp[256] = m4;
}

// ---------------- phase 2: exact carry + output ----------------
__global__ __launch_bounds__(64, 4) void pcen_phase2(
    const float* __restrict__ x, const float* __restrict__ s_p,
    const float* __restrict__ alpha_p, const float* __restrict__ delta_p,
    const float* __restrict__ r_p, const float* __restrict__ mloc,
    float* __restrict__ out) {
  const int b  = blockIdx.x;
  const int l  = threadIdx.x;
  const int bm = b >> 6;
  const int c  = b & (C - 1);

  const float s     = s_p[0];
  const float a     = 1.0f - s;
  const float alpha = alpha_p[0];
  const float delta = delta_p[0];
  const float r     = r_p[0];
  const float dr    = fast_exp2(r * fast_log2(delta));

  // a^L = a^32 via 5 squarings
  float aL = a;
  #pragma unroll
  for (int i = 0; i < 5; ++i) aL *= aL;

  const size_t rowoff = ((size_t)bm * T + (size_t)c * L) * F;
  const float* row  = x + rowoff;
  float*       orow = out + rowoff;

  // exact carry-in: E_{c-1} combined from chunk-local end states
  float m0, m1, m2, m3, m4;
  if (c == 0) {
    m0 = row[l]; m1 = row[l + 64]; m2 = row[l + 128]; m3 = row[l + 192];
    m4 = row[256];
  } else {
    const float* mp = mloc + (size_t)bm * C * F;   // cc = 0 row
    m0 = mp[l]; m1 = mp[l + 64]; m2 = mp[l + 128]; m3 = mp[l + 192];
    m4 = mp[256];
    const float* q = mp + F;
    #pragma unroll 2
    for (int cc = 1; cc < c; ++cc) {
      m0 = fmaf(aL, m0, q[l]);
      m1 = fmaf(aL, m1, q[l + 64]);
      m2 = fmaf(aL, m2, q[l + 128]);
      m3 = fmaf(aL, m3, q[l + 192]);
      m4 = fmaf(aL, m4, q[256]);
      q += F;
    }
  }

  const float* p  = row;
  float*       op = orow;
  #pragma unroll 2
  for (int t = 0; t < L; ++t) {
    float x0 = p[l];
    float x1 = p[l + 64];
    float x2 = p[l + 128];
    float x3 = p[l + 192];
    float x4 = p[256];
    m0 = fmaf(a, m0, s * x0);
    m1 = fmaf(a, m1, s * x1);
    m2 = fmaf(a, m2, s * x2);
    m3 = fmaf(a, m3, s * x3);
    m4 = fmaf(a, m4, s * x4);
    __builtin_nontemporal_store(pcen_nl(x0, m0, alpha, delta, r, dr), &op[l]);
    __builtin_nontemporal_store(pcen_nl(x1, m1, alpha, delta, r, dr), &op[l + 64]);
    __builtin_nontemporal_store(pcen_nl(x2, m2, alpha, delta, r, dr), &op[l + 128]);
    __builtin_nontemporal_store(pcen_nl(x3, m3, alpha, delta, r, dr), &op[l + 192]);
    if (l == 0)
      __builtin_nontemporal_store(pcen_nl(x4, m4, alpha, delta, r, dr), &op[256]);
    p  += F;
    op += F;
  }
}

// ---------------- fallback (no workspace): truncated single pass ----------
constexpr int FB_L = 128;
constexpr int FB_C = T / FB_L;
constexpr int FB_H = 256;
__global__ __launch_bounds__(64, 4) void pcen_fallback(
    const float* __restrict__ x, const float* __restrict__ s_p,
    const float* __restrict__ alpha_p, const float* __restrict__ delta_p,
    const float* __restrict__ r_p, float* __restrict__ out) {
  const int b  = blockIdx.x;
  const int l  = threadIdx.x;
  const int bm = b / FB_C;
  const int c  = b % FB_C;

  const float s     = s_p[0];
  const float a     = 1.0f - s;
  const float alpha = alpha_p[0];
  const float delta = delta_p[0];
  const float r     = r_p[0];
  const float dr    = fast_exp2(r * fast_log2(delta));

  const size_t colbase = (size_t)bm * T * F;
  const int tstart = c * FB_L;
  int t0 = tstart - FB_H; if (t0 < 0) t0 = 0;

  float m0, m1, m2, m3, m4;
  const float* row0 = x + colbase + (size_t)t0 * F;
  if (t0 == 0) {
    m0 = row0[l]; m1 = row0[l + 64]; m2 = row0[l + 128]; m3 = row0[l + 192];
    m4 = row0[256];
  } else {
    m0 = m1 = m2 = m3 = m4 = 0.0f;
  }

  const float* p = row0;
  for (int t = t0; t < tstart; ++t) {
    float x0 = p[l], x1 = p[l + 64], x2 = p[l + 128], x3 = p[l + 192], x4 = p[256];
    m0 = fmaf(a, m0, s * x0); m1 = fmaf(a, m1, s * x1);
    m2 = fmaf(a, m2, s * x2); m3 = fmaf(a, m3, s * x3);
    m4 = fmaf(a, m4, s * x4);
    p += F;
  }
  p = x + colbase + (size_t)tstart * F;
  float* op = out + colbase + (size_t)tstart * F;
  for (int t = 0; t < FB_L; ++t) {
    float x0 = p[l], x1 = p[l + 64], x2 = p[l + 128], x3 = p[l + 192], x4 = p[256];
    m0 = fmaf(a, m0, s * x0); m1 = fmaf(a, m1, s * x1);
    m2 = fmaf(a, m2, s * x2); m3 = fmaf(a, m3, s * x3);
    m4 = fmaf(a, m4, s * x4);
    __builtin_nontemporal_store(pcen_nl(x0, m0, alpha, delta, r, dr), &op[l]);
    __builtin_nontemporal_store(pcen_nl(x1, m1, alpha, delta, r, dr), &op[l + 64]);
    __builtin_nontemporal_store(pcen_nl(x2, m2, alpha, delta, r, dr), &op[l + 128]);
    __builtin_nontemporal_store(pcen_nl(x3, m3, alpha, delta, r, dr), &op[l + 192]);
    if (l == 0)
      __builtin_nontemporal_store(pcen_nl(x4, m4, alpha, delta, r, dr), &op[256]);
    p  += F;
    op += F;
  }
}

extern "C" void kernel_launch(void* const* d_in, const int* in_sizes, int n_in,
                              void* d_out, int out_size, void* d_ws, size_t ws_size,
                              hipStream_t stream) {
  const float* x     = (const float*)d_in[0];
  const float* s     = (const float*)d_in[1];
  const float* alpha = (const float*)d_in[2];
  const float* delta = (const float*)d_in[3];
  const float* r     = (const float*)d_in[4];
  float* out = (float*)d_out;

  if (d_ws != nullptr && ws_size >= MLOC_BYTES) {
    float* mloc = (float*)d_ws;
    pcen_phase1<<<NBLK, 64, 0, stream>>>(x, s, mloc);
    pcen_phase2<<<NBLK, 64, 0, stream>>>(x, s, alpha, delta, r, mloc, out);
  } else {
    pcen_fallback<<<BM * FB_C, 64, 0, stream>>>(x, s, alpha, delta, r, out);
  }
}

// Round 4
// 291.228 us; speedup vs baseline: 1.0621x; 1.0334x over previous
//
#include <hip/hip_runtime.h>

// StreamingPCEN: x [B=16, MICS=4, T=2048, F=257] fp32.
// M_t = (1-s) M_{t-1} + s x_t, M_0 = x_0; out = (x/(M+eps)^alpha + delta)^r - delta^r.
//
// Round-4 theory: all prior rounds streamed x with 4 B/lane dword loads and
// pinned at ~2.87 TB/s regardless of source-level MLP -- consistent with a
// per-CU outstanding-VMEM budget (~16 wave-instrs x 256 B / 900 cy = 4.6
// B/cy/CU). Fix: move bytes with 16 B/lane float4 instructions. F=257 rows
// (1028 B) are not 16B-aligned, but a 16-frame tile (16448 B) is -- so stage
// aligned float4 tiles into LDS and do the per-column strided reads from LDS
// (bank = (t + lane) mod 32 -> 2 lanes/bank = free).
//
// Structure: exact two-phase chunk scan (verified r2/r3).
//   phase1: block (bm, c) scans its L=128 chunk from zero state (c==0: from
//           the fixed point m=x_0), writes chunk-end state mloc[bm][c][f].
//   phase2: rebuilds the exact carry with <=15 fmas (a^128 by 7 squarings)
//           from L2-resident mloc, then emits the 128 output frames.
// Both phases: double-buffered LDS tiles (2 x 16448 B), T14 issue-early /
// write-late staging (global float4 loads -> compute current tile -> ds_write
// next tile -> barrier). 1024 blocks x 256 thr = 4 blocks/CU (LDS-limited),
// 16 waves/CU. Thread tid owns column f=tid; tid 0 also owns the f=256 tail.

#define EPS 1e-6f

constexpr int BM = 64;        // B*MICS
constexpr int T  = 2048;
constexpr int F  = 257;
constexpr int L  = 128;       // frames per chunk
constexpr int C  = T / L;     // 16 chunks
constexpr int TF = 16;        // frames per LDS tile (16*1028 B = 16448 B, 16B-aligned)
constexpr int NT = L / TF;    // 8 tiles per chunk
constexpr int NQ = TF * F / 4;  // 1028 float4 per tile
constexpr int BLKS = BM * C;    // 1024 blocks
constexpr size_t MLOC_BYTES = (size_t)BM * C * F * sizeof(float);  // ~1.03 MB

// Raw gfx950 hardware transcendentals (v_exp_f32 = 2^x, v_log_f32 = log2 x).
__device__ __forceinline__ float fast_exp2(float x) { return __builtin_amdgcn_exp2f(x); }
__device__ __forceinline__ float fast_log2(float x) { return __builtin_amdgcn_logf(x); }

__device__ __forceinline__ float pcen_nl(float xv, float m, float alpha,
                                         float delta, float r, float dr) {
  float inner = fmaf(xv, fast_exp2(-alpha * fast_log2(m + EPS)), delta);
  return fast_exp2(r * fast_log2(inner)) - dr;
}

// ---------------- phase 1: per-chunk local EMA end states ----------------
__global__ __launch_bounds__(256, 4) void pcen_phase1(
    const float* __restrict__ x, const float* __restrict__ s_p,
    float* __restrict__ mloc) {
  __shared__ float4 sb[2][NQ];
  const int tid = threadIdx.x;
  const int bm  = blockIdx.x >> 4;
  const int c   = blockIdx.x & (C - 1);

  const float s = s_p[0];
  const float a = 1.0f - s;

  const float* xb = x + (size_t)(bm * T + c * L) * F;   // float-offset %4==0 -> 16B aligned
  const float4* src = reinterpret_cast<const float4*>(xb);

  // stage tile 0
  {
    float4 v0 = src[tid], v1 = src[256 + tid], v2 = src[512 + tid], v3 = src[768 + tid];
    float4 vt = make_float4(0.f, 0.f, 0.f, 0.f);
    if (tid < 4) vt = src[1024 + tid];
    float4* dst = sb[0];
    dst[tid] = v0; dst[256 + tid] = v1; dst[512 + tid] = v2; dst[768 + tid] = v3;
    if (tid < 4) dst[1024 + tid] = vt;
  }
  __syncthreads();

  float m, mt = 0.0f;
  {
    const float* l0 = reinterpret_cast<const float*>(sb[0]);
    if (c == 0) {
      // fixed-point init: m = x_0 makes the frame-0 update a no-op, so the
      // uniform loop (including t=0) yields the exact end state.
      m = l0[tid];
      if (tid == 0) mt = l0[256];
    } else {
      m = 0.0f;
    }
  }

  for (int tt = 0; tt < NT; ++tt) {
    const float* lp = reinterpret_cast<const float*>(sb[tt & 1]);
    const bool more = (tt + 1 < NT);
    float4 v0, v1, v2, v3, vt = make_float4(0.f, 0.f, 0.f, 0.f);
    if (more) {                      // issue next-tile loads EARLY
      const float4* s2 = src + (size_t)(tt + 1) * NQ;
      v0 = s2[tid]; v1 = s2[256 + tid]; v2 = s2[512 + tid]; v3 = s2[768 + tid];
      if (tid < 4) vt = s2[1024 + tid];
    }
    // compute current tile from LDS (bank = (t+lane)%32 -> conflict-free)
    #pragma unroll
    for (int t = 0; t < TF; ++t) {
      float xv = lp[t * F + tid];
      m = fmaf(a, m, s * xv);
    }
    if (tid == 0) {
      #pragma unroll
      for (int t = 0; t < TF; ++t) mt = fmaf(a, mt, s * lp[t * F + 256]);
    }
    if (more) {                      // write staged tile LATE (latency hidden)
      float4* dst = sb[(tt & 1) ^ 1];
      dst[tid] = v0; dst[256 + tid] = v1; dst[512 + tid] = v2; dst[768 + tid] = v3;
      if (tid < 4) dst[1024 + tid] = vt;
    }
    __syncthreads();
  }

  float* mp = mloc + (size_t)(bm * C + c) * F;
  mp[tid] = m;
  if (tid == 0) mp[256] = mt;
}

// ---------------- phase 2: exact carry + output ----------------
__global__ __launch_bounds__(256, 4) void pcen_phase2(
    const float* __restrict__ x, const float* __restrict__ s_p,
    const float* __restrict__ alpha_p, const float* __restrict__ delta_p,
    const float* __restrict__ r_p, const float* __restrict__ mloc,
    float* __restrict__ out) {
  __shared__ float4 sb[2][NQ];
  const int tid = threadIdx.x;
  const int bm  = blockIdx.x >> 4;
  const int c   = blockIdx.x & (C - 1);

  const float s     = s_p[0];
  const float a     = 1.0f - s;
  const float alpha = alpha_p[0];
  const float delta = delta_p[0];
  const float r     = r_p[0];
  const float dr    = fast_exp2(r * fast_log2(delta));

  float aL = a;                    // a^128 via 7 squarings
  #pragma unroll
  for (int i = 0; i < 7; ++i) aL *= aL;

  const size_t rowoff = (size_t)(bm * T + c * L) * F;
  const float* xb = x + rowoff;
  float*       ob = out + rowoff;
  const float4* src = reinterpret_cast<const float4*>(xb);

  // exact carry-in E_{c-1}: fold chunk-local end states (L2-resident, <=15 fmas)
  float m = 0.0f, mt = 0.0f;
  if (c > 0) {
    const float* mp = mloc + (size_t)bm * C * F;
    m = mp[tid];
    if (tid == 0) mt = mp[256];
    #pragma unroll 4
    for (int cc = 1; cc < c; ++cc) {
      m = fmaf(aL, m, mp[cc * F + tid]);
      if (tid == 0) mt = fmaf(aL, mt, mp[cc * F + 256]);
    }
  }

  // stage tile 0
  {
    float4 v0 = src[tid], v1 = src[256 + tid], v2 = src[512 + tid], v3 = src[768 + tid];
    float4 vt = make_float4(0.f, 0.f, 0.f, 0.f);
    if (tid < 4) vt = src[1024 + tid];
    float4* dst = sb[0];
    dst[tid] = v0; dst[256 + tid] = v1; dst[512 + tid] = v2; dst[768 + tid] = v3;
    if (tid < 4) dst[1024 + tid] = vt;
  }
  __syncthreads();

  if (c == 0) {
    const float* l0 = reinterpret_cast<const float*>(sb[0]);
    m = l0[tid];
    mt = (tid == 0) ? l0[256] : 0.0f;
  }

  for (int tt = 0; tt < NT; ++tt) {
    const float* lp = reinterpret_cast<const float*>(sb[tt & 1]);
    float* op = ob + (size_t)tt * TF * F;
    const bool more = (tt + 1 < NT);
    float4 v0, v1, v2, v3, vt = make_float4(0.f, 0.f, 0.f, 0.f);
    if (more) {                      // issue next-tile loads EARLY
      const float4* s2 = src + (size_t)(tt + 1) * NQ;
      v0 = s2[tid]; v1 = s2[256 + tid]; v2 = s2[512 + tid]; v3 = s2[768 + tid];
      if (tid < 4) vt = s2[1024 + tid];
    }
    #pragma unroll
    for (int t = 0; t < TF; ++t) {
      float xv = lp[t * F + tid];
      m = fmaf(a, m, s * xv);
      __builtin_nontemporal_store(pcen_nl(xv, m, alpha, delta, r, dr),
                                  &op[t * F + tid]);
    }
    if (tid == 0) {
      #pragma unroll
      for (int t = 0; t < TF; ++t) {
        float xv = lp[t * F + 256];
        mt = fmaf(a, mt, s * xv);
        __builtin_nontemporal_store(pcen_nl(xv, mt, alpha, delta, r, dr),
                                    &op[t * F + 256]);
      }
    }
    if (more) {                      // write staged tile LATE
      float4* dst = sb[(tt & 1) ^ 1];
      dst[tid] = v0; dst[256 + tid] = v1; dst[512 + tid] = v2; dst[768 + tid] = v3;
      if (tid < 4) dst[1024 + tid] = vt;
    }
    __syncthreads();
  }
}

// ---------------- fallback (no workspace): truncated single pass ----------
constexpr int FB_L = 128;
constexpr int FB_C = T / FB_L;
constexpr int FB_H = 256;
__global__ __launch_bounds__(64, 4) void pcen_fallback(
    const float* __restrict__ x, const float* __restrict__ s_p,
    const float* __restrict__ alpha_p, const float* __restrict__ delta_p,
    const float* __restrict__ r_p, float* __restrict__ out) {
  const int b  = blockIdx.x;
  const int l  = threadIdx.x;
  const int bm = b / FB_C;
  const int c  = b % FB_C;

  const float s     = s_p[0];
  const float a     = 1.0f - s;
  const float alpha = alpha_p[0];
  const float delta = delta_p[0];
  const float r     = r_p[0];
  const float dr    = fast_exp2(r * fast_log2(delta));

  const size_t colbase = (size_t)bm * T * F;
  const int tstart = c * FB_L;
  int t0 = tstart - FB_H; if (t0 < 0) t0 = 0;

  float m0, m1, m2, m3, m4;
  const float* row0 = x + colbase + (size_t)t0 * F;
  if (t0 == 0) {
    m0 = row0[l]; m1 = row0[l + 64]; m2 = row0[l + 128]; m3 = row0[l + 192];
    m4 = row0[256];
  } else {
    m0 = m1 = m2 = m3 = m4 = 0.0f;
  }

  const float* p = row0;
  for (int t = t0; t < tstart; ++t) {
    float x0 = p[l], x1 = p[l + 64], x2 = p[l + 128], x3 = p[l + 192], x4 = p[256];
    m0 = fmaf(a, m0, s * x0); m1 = fmaf(a, m1, s * x1);
    m2 = fmaf(a, m2, s * x2); m3 = fmaf(a, m3, s * x3);
    m4 = fmaf(a, m4, s * x4);
    p += F;
  }
  p = x + colbase + (size_t)tstart * F;
  float* op = out + colbase + (size_t)tstart * F;
  for (int t = 0; t < FB_L; ++t) {
    float x0 = p[l], x1 = p[l + 64], x2 = p[l + 128], x3 = p[l + 192], x4 = p[256];
    m0 = fmaf(a, m0, s * x0); m1 = fmaf(a, m1, s * x1);
    m2 = fmaf(a, m2, s * x2); m3 = fmaf(a, m3, s * x3);
    m4 = fmaf(a, m4, s * x4);
    __builtin_nontemporal_store(pcen_nl(x0, m0, alpha, delta, r, dr), &op[l]);
    __builtin_nontemporal_store(pcen_nl(x1, m1, alpha, delta, r, dr), &op[l + 64]);
    __builtin_nontemporal_store(pcen_nl(x2, m2, alpha, delta, r, dr), &op[l + 128]);
    __builtin_nontemporal_store(pcen_nl(x3, m3, alpha, delta, r, dr), &op[l + 192]);
    if (l == 0)
      __builtin_nontemporal_store(pcen_nl(x4, m4, alpha, delta, r, dr), &op[256]);
    p  += F;
    op += F;
  }
}

extern "C" void kernel_launch(void* const* d_in, const int* in_sizes, int n_in,
                              void* d_out, int out_size, void* d_ws, size_t ws_size,
                              hipStream_t stream) {
  const float* x     = (const float*)d_in[0];
  const float* s     = (const float*)d_in[1];
  const float* alpha = (const float*)d_in[2];
  const float* delta = (const float*)d_in[3];
  const float* r     = (const float*)d_in[4];
  float* out = (float*)d_out;

  if (d_ws != nullptr && ws_size >= MLOC_BYTES) {
    float* mloc = (float*)d_ws;
    pcen_phase1<<<BLKS, 256, 0, stream>>>(x, s, mloc);
    pcen_phase2<<<BLKS, 256, 0, stream>>>(x, s, alpha, delta, r, mloc, out);
  } else {
    pcen_fallback<<<BM * FB_C, 64, 0, stream>>>(x, s, alpha, delta, r, out);
  }
}